// Round 3
// baseline (767.071 us; speedup 1.0000x reference)
//
#include <hip/hip_runtime.h>

#define BB 32
#define NN 2048
#define MM 512
#define DD 512
#define LDKH 40   // LDS row stride for K-step-32 tiles: 80 B rows (5 bank-quads, floor-rate)
#define LDK64 72  // LDS row stride for K-step-64 tiles: 144 B rows (9 quads ≡ 1 mod 8, floor-rate)

typedef _Float16 half4f __attribute__((ext_vector_type(4)));
typedef _Float16 half8f __attribute__((ext_vector_type(8)));
typedef float    f32x16 __attribute__((ext_vector_type(16)));

// K1: c1[b,n] = C[b,n,:]·w1 ; q2[b,m] = Q[b,m,:]·w2. One wave per row, 4 waves/block.
__global__ __launch_bounds__(256) void k_dots(const float* __restrict__ C, const float* __restrict__ Q,
                                              const float* __restrict__ w,
                                              float* __restrict__ c1, float* __restrict__ q2) {
    int wid  = blockIdx.x * 4 + (threadIdx.x >> 6);
    int lane = threadIdx.x & 63;
    const int NR1 = BB * NN;
    const float* src; const float* wv; float* dst;
    if (wid < NR1) { src = C + (size_t)wid * DD; wv = w;       dst = c1 + wid; }
    else { int r = wid - NR1; src = Q + (size_t)r * DD; wv = w + DD; dst = q2 + r; }
    float4 a0 = *(const float4*)(src + lane * 8);
    float4 a1 = *(const float4*)(src + lane * 8 + 4);
    float4 b0 = *(const float4*)(wv  + lane * 8);
    float4 b1 = *(const float4*)(wv  + lane * 8 + 4);
    float s = a0.x * b0.x + a0.y * b0.y + a0.z * b0.z + a0.w * b0.w
            + a1.x * b1.x + a1.y * b1.y + a1.z * b1.z + a1.w * b1.w;
#pragma unroll
    for (int o = 32; o > 0; o >>= 1) s += __shfl_down(s, o);
    if (lane == 0) *dst = s;
}

// K1b: from Q emit (a) Qt[b,d,m] fp16 transposed with Qmask folded (k_AB B-operand),
// (b) Qh/Ql[b,m,d]: 2-term fp16 split of Q, unmasked (k_sgemm B-operand).
__global__ __launch_bounds__(256) void k_prepQ(const float* __restrict__ Q, const int* __restrict__ Qmask,
                                               _Float16* __restrict__ Qt,
                                               _Float16* __restrict__ Qh, _Float16* __restrict__ Ql) {
    __shared__ float Ls[64][65];
    const int bid = blockIdx.x;          // BB * 8 * 8
    const int b   = bid >> 6;
    const int rem = bid & 63;
    const int m0  = (rem >> 3) << 6;
    const int d0  = (rem & 7) << 6;
    const int tid = threadIdx.x;
    const int r   = tid >> 4;
    const int c4  = (tid & 15) << 2;
#pragma unroll
    for (int p = 0; p < 4; ++p) {
        const int m = r + (p << 4);
        const size_t o = ((size_t)(b * MM + m0 + m)) * DD + d0 + c4;
        float4 v = *(const float4*)(Q + o);
        Ls[c4 + 0][m] = v.x; Ls[c4 + 1][m] = v.y; Ls[c4 + 2][m] = v.z; Ls[c4 + 3][m] = v.w;
        half4f hh, ll;
        float x0 = v.x, x1 = v.y, x2 = v.z, x3 = v.w;
        hh[0] = (_Float16)x0; ll[0] = (_Float16)((x0 - (float)hh[0]) * 2048.f);
        hh[1] = (_Float16)x1; ll[1] = (_Float16)((x1 - (float)hh[1]) * 2048.f);
        hh[2] = (_Float16)x2; ll[2] = (_Float16)((x2 - (float)hh[2]) * 2048.f);
        hh[3] = (_Float16)x3; ll[3] = (_Float16)((x3 - (float)hh[3]) * 2048.f);
        *(half4f*)&Qh[o] = hh;
        *(half4f*)&Ql[o] = ll;
    }
    __syncthreads();
    float z[4];
#pragma unroll
    for (int i = 0; i < 4; ++i) z[i] = Qmask[b * MM + m0 + c4 + i] ? 0.f : 1.f;
#pragma unroll
    for (int p = 0; p < 4; ++p) {
        const int d = r + (p << 4);
        half4f o;
#pragma unroll
        for (int i = 0; i < 4; ++i) o[i] = (_Float16)(Ls[d][c4 + i] * z[i]);
        *(half4f*)&Qt[((size_t)(b * DD + d0 + d)) * MM + m0 + c4] = o;
    }
}

// K1c: from C emit (a) Ct[b,d,n] fp16 transposed (k_T A-operand),
// (b) Ch/Cl[b,n,d]: 2-term fp16 split of C*w3 (k_sgemm A-operand).
__global__ __launch_bounds__(256) void k_prepC(const float* __restrict__ C, const float* __restrict__ w,
                                               _Float16* __restrict__ Ct,
                                               _Float16* __restrict__ Ch, _Float16* __restrict__ Cl) {
    __shared__ float Ls[64][65];
    const int bid = blockIdx.x;          // BB * 32 * 8
    const int b   = bid >> 8;
    const int nn0 = ((bid >> 3) & 31) << 6;
    const int dd0 = (bid & 7) << 6;
    const int tid = threadIdx.x;
    const int r   = tid >> 4;
    const int c4  = (tid & 15) << 2;
    const float* w3 = w + 2 * DD;
    const float4 wv = *(const float4*)(w3 + dd0 + c4);
#pragma unroll
    for (int p = 0; p < 4; ++p) {
        const int n = r + (p << 4);
        const size_t o = ((size_t)(b * NN + nn0 + n)) * DD + dd0 + c4;
        float4 v = *(const float4*)(C + o);
        Ls[c4 + 0][n] = v.x; Ls[c4 + 1][n] = v.y; Ls[c4 + 2][n] = v.z; Ls[c4 + 3][n] = v.w;
        float x0 = v.x * wv.x, x1 = v.y * wv.y, x2 = v.z * wv.z, x3 = v.w * wv.w;
        half4f hh, ll;
        hh[0] = (_Float16)x0; ll[0] = (_Float16)((x0 - (float)hh[0]) * 2048.f);
        hh[1] = (_Float16)x1; ll[1] = (_Float16)((x1 - (float)hh[1]) * 2048.f);
        hh[2] = (_Float16)x2; ll[2] = (_Float16)((x2 - (float)hh[2]) * 2048.f);
        hh[3] = (_Float16)x3; ll[3] = (_Float16)((x3 - (float)hh[3]) * 2048.f);
        *(half4f*)&Ch[o] = hh;
        *(half4f*)&Cl[o] = ll;
    }
    __syncthreads();
#pragma unroll
    for (int p = 0; p < 4; ++p) {
        const int d = r + (p << 4);
        half4f o;
#pragma unroll
        for (int i = 0; i < 4; ++i) o[i] = (_Float16)Ls[d][c4 + i];
        *(half4f*)&Ct[((size_t)(b * DD + dd0 + d)) * NN + nn0 + c4] = o;
    }
}

// K2b: Et[b,m,n] = E[b,n,m] with Cmask(n)-masked entries zeroed (k_T's B-operand).
__global__ __launch_bounds__(256) void k_te(const _Float16* __restrict__ E, const int* __restrict__ Cmask,
                                            _Float16* __restrict__ Et) {
    __shared__ float Ls[64][65];
    const int bid = blockIdx.x;          // BB * 32 * 8
    const int b   = bid >> 8;
    const int nn0 = ((bid >> 3) & 31) << 6;
    const int mm0 = (bid & 7) << 6;
    const int tid = threadIdx.x;
    const int r   = tid >> 4;
    const int c4  = (tid & 15) << 2;
#pragma unroll
    for (int p = 0; p < 4; ++p) {
        const int n = r + (p << 4);
        half4f v = *(const half4f*)&E[((size_t)(b * NN + nn0 + n)) * MM + mm0 + c4];
        const float z = Cmask[b * NN + nn0 + n] ? 0.f : 1.f;
        Ls[c4 + 0][n] = (float)v[0] * z; Ls[c4 + 1][n] = (float)v[1] * z;
        Ls[c4 + 2][n] = (float)v[2] * z; Ls[c4 + 3][n] = (float)v[3] * z;
    }
    __syncthreads();
#pragma unroll
    for (int p = 0; p < 4; ++p) {
        const int m = r + (p << 4);
        half4f o;
#pragma unroll
        for (int i = 0; i < 4; ++i) o[i] = (_Float16)Ls[m][c4 + i];
        *(half4f*)&Et[((size_t)(b * MM + mm0 + m)) * NN + nn0 + c4] = o;
    }
}

// K2 (MFMA, pre-split operands): S = Ah·Bh + 2^-11(Ah·Bl + Al·Bh).
// E[b,n,m] = fp16(exp(S + c1 + q2)); masked row/col sums of the QUANTIZED exp -> rsum/csum.
// 128x128 tile, 4 waves 2x2, 64x64/wave, K-step 32 over d, T14 prefetch.
__global__ __launch_bounds__(256, 2) void k_sgemm(const _Float16* __restrict__ Ch, const _Float16* __restrict__ Cl,
                                                  const _Float16* __restrict__ Qh, const _Float16* __restrict__ Ql,
                                                  const int* __restrict__ Cmask, const int* __restrict__ Qmask,
                                                  const float* __restrict__ c1, const float* __restrict__ q2,
                                                  _Float16* __restrict__ E, float* __restrict__ rsum,
                                                  float* __restrict__ csum) {
    __shared__ _Float16 sAh[128 * LDKH], sAl[128 * LDKH], sBh[128 * LDKH], sBl[128 * LDKH];
    __shared__ float rowp[128], colp[128], cmz[128], qmz[128], c1s[128], q2s[128];
    const int hw  = blockIdx.x;
    const int bid = ((hw & 7) << 8) | (hw >> 3);   // XCD-chunked swizzle, 2048 = 8*256
    const int b   = bid >> 6;
    const int rem = bid & 63;
    const int n0  = (rem >> 2) << 7;
    const int m0  = (rem & 3) << 7;
    const int tid = threadIdx.x;
    const int lane = tid & 63;
    const int wid  = tid >> 6;
    const int wr = wid >> 1, wc = wid & 1;
    const int srow = tid >> 2;           // 0..63 (and +64)
    const int sseg = (tid & 3) << 3;     // halves 0,8,16,24
    if (tid < 128) {
        rowp[tid] = 0.f; colp[tid] = 0.f;
        cmz[tid] = Cmask[b * NN + n0 + tid] ? 0.f : 1.f;
        c1s[tid] = c1[b * NN + n0 + tid];
    } else {
        const int t = tid - 128;
        qmz[t] = Qmask[b * MM + m0 + t] ? 0.f : 1.f;
        q2s[t] = q2[b * MM + m0 + t];
    }
    const _Float16* gAh = Ch + ((size_t)(b * NN + n0 + srow)) * DD + sseg;
    const _Float16* gAl = Cl + ((size_t)(b * NN + n0 + srow)) * DD + sseg;
    const _Float16* gBh = Qh + ((size_t)(b * MM + m0 + srow)) * DD + sseg;
    const _Float16* gBl = Ql + ((size_t)(b * MM + m0 + srow)) * DD + sseg;
    const int wofs0 = srow * LDKH + sseg;
    const int wofs1 = (srow + 64) * LDKH + sseg;
    half8f pah0 = *(const half8f*)(gAh);
    half8f pah1 = *(const half8f*)(gAh + (size_t)64 * DD);
    half8f pal0 = *(const half8f*)(gAl);
    half8f pal1 = *(const half8f*)(gAl + (size_t)64 * DD);
    half8f pbh0 = *(const half8f*)(gBh);
    half8f pbh1 = *(const half8f*)(gBh + (size_t)64 * DD);
    half8f pbl0 = *(const half8f*)(gBl);
    half8f pbl1 = *(const half8f*)(gBl + (size_t)64 * DD);
    f32x16 accH[2][2] = {};
    f32x16 accX[2][2] = {};
    const int ar  = wr * 64 + (lane & 31);
    const int bc  = wc * 64 + (lane & 31);
    const int kof = (lane >> 5) << 3;
    for (int it = 0; it < 16; ++it) {
        __syncthreads();
        *(half8f*)&sAh[wofs0] = pah0; *(half8f*)&sAh[wofs1] = pah1;
        *(half8f*)&sAl[wofs0] = pal0; *(half8f*)&sAl[wofs1] = pal1;
        *(half8f*)&sBh[wofs0] = pbh0; *(half8f*)&sBh[wofs1] = pbh1;
        *(half8f*)&sBl[wofs0] = pbl0; *(half8f*)&sBl[wofs1] = pbl1;
        __syncthreads();
        if (it < 15) {      // issue next-tile loads BEFORE the MFMA section (T14)
            const int k0 = (it + 1) << 5;
            pah0 = *(const half8f*)(gAh + k0);
            pah1 = *(const half8f*)(gAh + k0 + (size_t)64 * DD);
            pal0 = *(const half8f*)(gAl + k0);
            pal1 = *(const half8f*)(gAl + k0 + (size_t)64 * DD);
            pbh0 = *(const half8f*)(gBh + k0);
            pbh1 = *(const half8f*)(gBh + k0 + (size_t)64 * DD);
            pbl0 = *(const half8f*)(gBl + k0);
            pbl1 = *(const half8f*)(gBl + k0 + (size_t)64 * DD);
        }
#pragma unroll
        for (int h = 0; h < 2; ++h) {
            const int ko = (h << 4) + kof;
            half8f ah0 = *(const half8f*)&sAh[ar * LDKH + ko];
            half8f ah1 = *(const half8f*)&sAh[(ar + 32) * LDKH + ko];
            half8f al0 = *(const half8f*)&sAl[ar * LDKH + ko];
            half8f al1 = *(const half8f*)&sAl[(ar + 32) * LDKH + ko];
            half8f bh0 = *(const half8f*)&sBh[bc * LDKH + ko];
            half8f bh1 = *(const half8f*)&sBh[(bc + 32) * LDKH + ko];
            half8f bl0 = *(const half8f*)&sBl[bc * LDKH + ko];
            half8f bl1 = *(const half8f*)&sBl[(bc + 32) * LDKH + ko];
            accH[0][0] = __builtin_amdgcn_mfma_f32_32x32x16_f16(ah0, bh0, accH[0][0], 0, 0, 0);
            accH[0][1] = __builtin_amdgcn_mfma_f32_32x32x16_f16(ah0, bh1, accH[0][1], 0, 0, 0);
            accH[1][0] = __builtin_amdgcn_mfma_f32_32x32x16_f16(ah1, bh0, accH[1][0], 0, 0, 0);
            accH[1][1] = __builtin_amdgcn_mfma_f32_32x32x16_f16(ah1, bh1, accH[1][1], 0, 0, 0);
            accX[0][0] = __builtin_amdgcn_mfma_f32_32x32x16_f16(ah0, bl0, accX[0][0], 0, 0, 0);
            accX[0][0] = __builtin_amdgcn_mfma_f32_32x32x16_f16(al0, bh0, accX[0][0], 0, 0, 0);
            accX[0][1] = __builtin_amdgcn_mfma_f32_32x32x16_f16(ah0, bl1, accX[0][1], 0, 0, 0);
            accX[0][1] = __builtin_amdgcn_mfma_f32_32x32x16_f16(al0, bh1, accX[0][1], 0, 0, 0);
            accX[1][0] = __builtin_amdgcn_mfma_f32_32x32x16_f16(ah1, bl0, accX[1][0], 0, 0, 0);
            accX[1][0] = __builtin_amdgcn_mfma_f32_32x32x16_f16(al1, bh0, accX[1][0], 0, 0, 0);
            accX[1][1] = __builtin_amdgcn_mfma_f32_32x32x16_f16(ah1, bl1, accX[1][1], 0, 0, 0);
            accX[1][1] = __builtin_amdgcn_mfma_f32_32x32x16_f16(al1, bh1, accX[1][1], 0, 0, 0);
        }
    }
    // epilogue: C/D layout col=lane&31, row=(r&3)+8*(r>>2)+4*(lane>>5)  (identical to round-2)
    const float inv2k = 4.8828125e-4f;  // 2^-11
    const int mcol0 = wc * 64 + (lane & 31);
    const float qz0 = qmz[mcol0], qz1 = qmz[mcol0 + 32];
    const float q2v0 = q2s[mcol0], q2v1 = q2s[mcol0 + 32];
    const int hi4 = (lane >> 5) << 2;
    float colacc0 = 0.f, colacc1 = 0.f;
#pragma unroll
    for (int i = 0; i < 2; ++i) {
#pragma unroll
        for (int r = 0; r < 16; ++r) {
            const int nloc = wr * 64 + i * 32 + (r & 3) + ((r >> 2) << 3) + hi4;
            const float base = c1s[nloc];
            float S0 = accH[i][0][r] + accX[i][0][r] * inv2k + base + q2v0;
            float S1 = accH[i][1][r] + accX[i][1][r] * inv2k + base + q2v1;
            float e0 = __expf(S0), e1 = __expf(S1);
            _Float16 h0 = (_Float16)e0, h1 = (_Float16)e1;
            float eq0 = (float)h0, eq1 = (float)h1;
            const size_t erow = ((size_t)(b * NN + n0 + nloc)) * MM + m0;
            E[erow + mcol0]      = h0;
            E[erow + mcol0 + 32] = h1;
            const float cz = cmz[nloc];
            colacc0 += eq0 * cz;
            colacc1 += eq1 * cz;
            float rv = eq0 * qz0 + eq1 * qz1;
            rv += __shfl_xor(rv, 1);  rv += __shfl_xor(rv, 2);
            rv += __shfl_xor(rv, 4);  rv += __shfl_xor(rv, 8);
            rv += __shfl_xor(rv, 16);
            if ((lane & 31) == 0) atomicAdd(&rowp[nloc], rv);
        }
    }
    atomicAdd(&colp[mcol0], colacc0);
    atomicAdd(&colp[mcol0 + 32], colacc1);
    __syncthreads();
    if (tid < 128) atomicAdd(&rsum[b * NN + n0 + tid], rowp[tid]);
    else atomicAdd(&csum[b * MM + m0 + tid - 128], colp[tid - 128]);
}

// K3 (MFMA): Tt[b,d,m] = fp16( (1/csum[m]) * qz[m] * sum_n Ct[d,n]*Et[m,n] ).
// 128(d) x 128(m) tile, K = N = 2048, K-step 64, T14 prefetch, 3 blocks/CU.
__global__ __launch_bounds__(256, 3) void k_T(const _Float16* __restrict__ Ct,
                                              const _Float16* __restrict__ Et,
                                              const float* __restrict__ csum,
                                              const int* __restrict__ Qmask,
                                              _Float16* __restrict__ Tt) {
    __shared__ _Float16 As[128 * LDK64];
    __shared__ _Float16 Bs[128 * LDK64];
    const int hw  = blockIdx.x;                    // 512
    const int bid = ((hw & 7) << 6) | (hw >> 3);   // 512 = 8*64, bijective
    const int b   = bid >> 4;
    const int rem = bid & 15;
    const int d0  = (rem >> 2) << 7;
    const int m0  = (rem & 3) << 7;
    const int tid = threadIdx.x;
    const int lane = tid & 63;
    const int wid  = tid >> 6;
    const int wr = wid >> 1, wc = wid & 1;
    const int srow = tid >> 3;            // 0..31 (+32p)
    const int sseg = (tid & 7) << 3;      // halves 0..56
    const _Float16* g0 = Ct + ((size_t)(b * DD + d0 + srow)) * NN + sseg;
    const _Float16* g1 = Et + ((size_t)(b * MM + m0 + srow)) * NN + sseg;
    const int wofs = srow * LDK64 + sseg;
    half8f pa[4], pb[4];
#pragma unroll
    for (int p = 0; p < 4; ++p) {
        pa[p] = *(const half8f*)(g0 + (size_t)(p * 32) * NN);
        pb[p] = *(const half8f*)(g1 + (size_t)(p * 32) * NN);
    }
    f32x16 acc[2][2] = {};
    const int ar  = wr * 64 + (lane & 31);
    const int bc  = wc * 64 + (lane & 31);
    const int kof = (lane >> 5) << 3;
    for (int it = 0; it < 32; ++it) {
        __syncthreads();
#pragma unroll
        for (int p = 0; p < 4; ++p) {
            *(half8f*)&As[wofs + p * 32 * LDK64] = pa[p];
            *(half8f*)&Bs[wofs + p * 32 * LDK64] = pb[p];
        }
        __syncthreads();
        if (it < 31) {
            const int k0 = (it + 1) << 6;
#pragma unroll
            for (int p = 0; p < 4; ++p) {
                pa[p] = *(const half8f*)(g0 + (size_t)(p * 32) * NN + k0);
                pb[p] = *(const half8f*)(g1 + (size_t)(p * 32) * NN + k0);
            }
        }
#pragma unroll
        for (int h = 0; h < 4; ++h) {
            const int ko = (h << 4) + kof;
            half8f a0 = *(const half8f*)&As[ar * LDK64 + ko];
            half8f a1 = *(const half8f*)&As[(ar + 32) * LDK64 + ko];
            half8f b0 = *(const half8f*)&Bs[bc * LDK64 + ko];
            half8f b1 = *(const half8f*)&Bs[(bc + 32) * LDK64 + ko];
            acc[0][0] = __builtin_amdgcn_mfma_f32_32x32x16_f16(a0, b0, acc[0][0], 0, 0, 0);
            acc[0][1] = __builtin_amdgcn_mfma_f32_32x32x16_f16(a0, b1, acc[0][1], 0, 0, 0);
            acc[1][0] = __builtin_amdgcn_mfma_f32_32x32x16_f16(a1, b0, acc[1][0], 0, 0, 0);
            acc[1][1] = __builtin_amdgcn_mfma_f32_32x32x16_f16(a1, b1, acc[1][1], 0, 0, 0);
        }
    }
    const int mc0 = m0 + wc * 64 + (lane & 31);
    const float s0 = (Qmask[b * MM + mc0]      ? 0.f : 1.f) / csum[b * MM + mc0];
    const float s1 = (Qmask[b * MM + mc0 + 32] ? 0.f : 1.f) / csum[b * MM + mc0 + 32];
    const int hi4 = (lane >> 5) << 2;
#pragma unroll
    for (int i = 0; i < 2; ++i) {
#pragma unroll
        for (int r = 0; r < 16; ++r) {
            const int d = d0 + wr * 64 + i * 32 + (r & 3) + ((r >> 2) << 3) + hi4;
            const size_t o = ((size_t)(b * DD + d)) * MM + mc0;
            Tt[o]      = (_Float16)(acc[i][0][r] * s0);
            Tt[o + 32] = (_Float16)(acc[i][1][r] * s1);
        }
    }
}

// K4 (MFMA): A[b,n,d] = (1/rsum[n]) * sum_m E[n,m]*Qt[d,m]; Bout likewise with Tt.
// K-step 64 (8 iters), T14 prefetch.
__global__ __launch_bounds__(256, 2) void k_AB(const _Float16* __restrict__ E,
                                               const _Float16* __restrict__ Qt,
                                               const _Float16* __restrict__ Tt,
                                               const float* __restrict__ rsum,
                                               float* __restrict__ outA, float* __restrict__ outB) {
    __shared__ _Float16 Es[128 * LDK64];
    __shared__ _Float16 Ws[2][128 * LDK64];
    const int hw  = blockIdx.x;
    const int bid = ((hw & 7) << 8) | (hw >> 3);
    const int b   = bid >> 6;
    const int rem = bid & 63;
    const int n0  = (rem >> 2) << 7;
    const int d0  = (rem & 3) << 7;
    const int tid = threadIdx.x;
    const int lane = tid & 63;
    const int wid  = tid >> 6;
    const int wr = wid >> 1, wc = wid & 1;
    const int srow = tid >> 3;            // 0..31 (+32p)
    const int sseg = (tid & 7) << 3;      // halves 0..56
    const _Float16* g0 = E  + ((size_t)(b * NN + n0 + srow)) * MM + sseg;
    const _Float16* g1 = Qt + ((size_t)(b * DD + d0 + srow)) * MM + sseg;
    const _Float16* g2 = Tt + ((size_t)(b * DD + d0 + srow)) * MM + sseg;
    const int wofs = srow * LDK64 + sseg;
    half8f pe[4], pq[4], pt[4];
#pragma unroll
    for (int p = 0; p < 4; ++p) {
        pe[p] = *(const half8f*)(g0 + (size_t)(p * 32) * MM);
        pq[p] = *(const half8f*)(g1 + (size_t)(p * 32) * MM);
        pt[p] = *(const half8f*)(g2 + (size_t)(p * 32) * MM);
    }
    f32x16 accA[2][2] = {};
    f32x16 accB[2][2] = {};
    const int ar  = wr * 64 + (lane & 31);
    const int bc  = wc * 64 + (lane & 31);
    const int kof = (lane >> 5) << 3;
    for (int it = 0; it < 8; ++it) {
        __syncthreads();
#pragma unroll
        for (int p = 0; p < 4; ++p) {
            *(half8f*)&Es[wofs + p * 32 * LDK64]    = pe[p];
            *(half8f*)&Ws[0][wofs + p * 32 * LDK64] = pq[p];
            *(half8f*)&Ws[1][wofs + p * 32 * LDK64] = pt[p];
        }
        __syncthreads();
        if (it < 7) {
            const int k0 = (it + 1) << 6;
#pragma unroll
            for (int p = 0; p < 4; ++p) {
                pe[p] = *(const half8f*)(g0 + (size_t)(p * 32) * MM + k0);
                pq[p] = *(const half8f*)(g1 + (size_t)(p * 32) * MM + k0);
                pt[p] = *(const half8f*)(g2 + (size_t)(p * 32) * MM + k0);
            }
        }
#pragma unroll
        for (int h = 0; h < 4; ++h) {
            const int ko = (h << 4) + kof;
            half8f a0  = *(const half8f*)&Es[ar * LDK64 + ko];
            half8f a1  = *(const half8f*)&Es[(ar + 32) * LDK64 + ko];
            half8f bq0 = *(const half8f*)&Ws[0][bc * LDK64 + ko];
            half8f bq1 = *(const half8f*)&Ws[0][(bc + 32) * LDK64 + ko];
            half8f bt0 = *(const half8f*)&Ws[1][bc * LDK64 + ko];
            half8f bt1 = *(const half8f*)&Ws[1][(bc + 32) * LDK64 + ko];
            accA[0][0] = __builtin_amdgcn_mfma_f32_32x32x16_f16(a0, bq0, accA[0][0], 0, 0, 0);
            accA[0][1] = __builtin_amdgcn_mfma_f32_32x32x16_f16(a0, bq1, accA[0][1], 0, 0, 0);
            accA[1][0] = __builtin_amdgcn_mfma_f32_32x32x16_f16(a1, bq0, accA[1][0], 0, 0, 0);
            accA[1][1] = __builtin_amdgcn_mfma_f32_32x32x16_f16(a1, bq1, accA[1][1], 0, 0, 0);
            accB[0][0] = __builtin_amdgcn_mfma_f32_32x32x16_f16(a0, bt0, accB[0][0], 0, 0, 0);
            accB[0][1] = __builtin_amdgcn_mfma_f32_32x32x16_f16(a0, bt1, accB[0][1], 0, 0, 0);
            accB[1][0] = __builtin_amdgcn_mfma_f32_32x32x16_f16(a1, bt0, accB[1][0], 0, 0, 0);
            accB[1][1] = __builtin_amdgcn_mfma_f32_32x32x16_f16(a1, bt1, accB[1][1], 0, 0, 0);
        }
    }
    const int dc = d0 + wc * 64 + (lane & 31);
#pragma unroll
    for (int i = 0; i < 2; ++i) {
#pragma unroll
        for (int r = 0; r < 16; ++r) {
            const int row = (r & 3) + ((r >> 2) << 3) + ((lane >> 5) << 2);
            const int n = n0 + wr * 64 + i * 32 + row;
            const float inv = __builtin_amdgcn_rcpf(rsum[b * NN + n]);
            const size_t o = ((size_t)(b * NN + n)) * DD + dc;
            outA[o]      = accA[i][0][r] * inv;
            outA[o + 32] = accA[i][1][r] * inv;
            outB[o]      = accB[i][0][r] * inv;
            outB[o + 32] = accB[i][1][r] * inv;
        }
    }
}

extern "C" void kernel_launch(void* const* d_in, const int* in_sizes, int n_in,
                              void* d_out, int out_size, void* d_ws, size_t ws_size,
                              hipStream_t stream) {
    const float* C = (const float*)d_in[0];
    const float* Q = (const float*)d_in[1];
    const int* Cmask = (const int*)d_in[2];
    const int* Qmask = (const int*)d_in[3];
    const float* w  = (const float*)d_in[4];

    const size_t BNM = (size_t)BB * NN * MM;   // 33.55M halves
    const size_t BMD = (size_t)BB * MM * DD;   // 8.39M halves
    const size_t BND = (size_t)BB * NN * DD;   // 33.55M halves
    const size_t BN  = (size_t)BB * NN;
    const size_t BM  = (size_t)BB * MM;

    // Workspace (d_ws): E, Tt, Qt + small fp32 vectors (~101 MB, same as round 2).
    _Float16* E  = (_Float16*)d_ws;
    _Float16* Tt = E + BNM;
    _Float16* Qt = Tt + BMD;
    float* fbase = (float*)(Qt + BMD);
    float* c1   = fbase;
    float* q2   = c1 + BN;
    float* rsum = q2 + BM;
    float* csum = rsum + BN;

    // Scratch stashed in d_out (268.4 MB total):
    //   [Ct | Ch | Cl | Qh | Ql] = 67+67+67+16.8+16.8 = 234.9 MB.
    //   Ch/Cl/Qh/Ql dead after k_sgemm; Et reuses the Ch slot; Ct/Et dead after k_T;
    //   k_AB then overwrites d_out entirely with outA/outB.
    _Float16* Ct = (_Float16*)d_out;
    _Float16* Ch = Ct + BND;
    _Float16* Cl = Ch + BND;
    _Float16* Qh = Cl + BND;
    _Float16* Ql = Qh + BMD;
    _Float16* Et = Ch;   // reuse after k_sgemm

    hipMemsetAsync(rsum, 0, (BN + BM) * sizeof(float), stream);

    k_dots<<<(int)((BN + BM) / 4), 256, 0, stream>>>(C, Q, w, c1, q2);
    k_prepQ<<<BB * 64, 256, 0, stream>>>(Q, Qmask, Qt, Qh, Ql);
    k_prepC<<<BB * 256, 256, 0, stream>>>(C, w, Ct, Ch, Cl);
    k_sgemm<<<2048, 256, 0, stream>>>(Ch, Cl, Qh, Ql, Cmask, Qmask, c1, q2, E, rsum, csum);
    k_te<<<BB * 256, 256, 0, stream>>>(E, Cmask, Et);
    k_T<<<512, 256, 0, stream>>>(Ct, Et, csum, Qmask, Tt);
    k_AB<<<2048, 256, 0, stream>>>(E, Qt, Tt, rsum,
                                   (float*)d_out, (float*)d_out + BND);
}